// Round 1
// baseline (142.285 us; speedup 1.0000x reference)
//
#include <hip/hip_runtime.h>

#define NBK 10
#define KK  9

constexpr int Bv  = 4;
constexpr int Vv  = 5023;
constexpr int TOT = Bv * Vv;   // 20092

// ---------------------------------------------------------------------------
// Encoder: h0 = relu(x @ Win), ux0 = h0 @ u0.  One thread per vertex.
// ---------------------------------------------------------------------------
__global__ __launch_bounds__(256) void encoder_kernel(
    const float* __restrict__ x,     // [TOT,3]
    const float* __restrict__ Win,   // [3,16]
    const float* __restrict__ u0,    // [16,9]
    float* __restrict__ h,           // [TOT,16]
    float* __restrict__ ux)          // [TOT,9]
{
    int vv = blockIdx.x * 256 + threadIdx.x;
    if (vv >= TOT) return;
    float x0 = x[vv * 3 + 0], x1 = x[vv * 3 + 1], x2 = x[vv * 3 + 2];
    float hv[16];
#pragma unroll
    for (int c = 0; c < 16; c++) {
        float s = x0 * Win[c] + x1 * Win[16 + c] + x2 * Win[32 + c];
        hv[c] = fmaxf(s, 0.0f);
        h[(size_t)vv * 16 + c] = hv[c];
    }
#pragma unroll
    for (int k = 0; k < KK; k++) {
        float s = 0.0f;
#pragma unroll
        for (int c = 0; c < 16; c++) s = fmaf(hv[c], u0[c * KK + k], s);
        ux[(size_t)vv * KK + k] = s;
    }
}

// ---------------------------------------------------------------------------
// NLayer: 16 lanes per vertex, 16 vertices per 256-thread block.
//   hin  [TOT,CIN]  uxin [TOT,9]  ->  hout [TOT,COUT]  uxout [TOT,9]
//   LAST: fuse final h @ Wout into dout [TOT,3]
// ---------------------------------------------------------------------------
template<int CIN, int COUT, bool LAST>
__global__ __launch_bounds__(256) void nlayer_kernel(
    const float* __restrict__ hin,
    const float* __restrict__ uxin,
    const int*   __restrict__ adj,    // [Vv,NBK]
    const float* __restrict__ W,      // [CIN,KK,COUT]
    const float* __restrict__ bvec,   // [COUT]
    const float* __restrict__ cvec,   // [KK]
    const float* __restrict__ unext,  // [COUT,KK]  (or Wout [3,3] if LAST)
    float* __restrict__ hout,
    float* __restrict__ uxout,
    float* __restrict__ dout)
{
    constexpr int CP = CIN + 4;   // pad so group stride != 0 mod 32 banks
    constexpr int WP = CIN + 1;   // odd stride -> conflict-free staging+reads

    __shared__ __align__(16) float s_hnb[16][NBK][CP];
    __shared__ float s_lg[16][NBK][KK];   // logits -> q
    __shared__ float s_uxs[16][KK];
    __shared__ int   s_adj[16][NBK];
    __shared__ float s_rec[16];
    __shared__ float s_hnew[16][COUT];
    __shared__ float s_w[KK][COUT][WP];   // W transposed: [k][o][c]

    const int tid = threadIdx.x;
    const int g = tid >> 4;
    const int t = tid & 15;
    const int vv = blockIdx.x * 16 + g;
    const bool act = vv < TOT;
    int b = 0, v = 0;
    if (act) { b = vv / Vv; v = vv - b * Vv; }

    // Stage W transposed into LDS (global reads coalesced; odd LDS stride)
    for (int i = tid; i < CIN * KK * COUT; i += 256) {
        int c = i / (KK * COUT);
        int rem = i - c * (KK * COUT);
        int k = rem / COUT;
        int o = rem - k * COUT;
        s_w[k][o][c] = W[i];
    }

    if (act) {
        if (t < NBK) s_adj[g][t] = adj[v * NBK + t];
        if (t < KK)  s_uxs[g][t] = uxin[(size_t)vv * KK + t];
    }
    __syncthreads();

    if (act && t == 0) {
        int cnt = 0;
#pragma unroll
        for (int n = 0; n < NBK; n++) cnt += (s_adj[g][n] != 0) ? 1 : 0;
        s_rec[g] = (cnt > 0) ? (1.0f / (float)cnt) : 0.0f;
    }

    if (act) {
        // Gather neighbor features h_nb -> LDS (float4)
        constexpr int U = NBK * CIN / 4;
        for (int j = t; j < U; j += 16) {
            int n  = j / (CIN / 4);
            int c4 = j - n * (CIN / 4);
            int a = s_adj[g][n];
            float4 val = {0.0f, 0.0f, 0.0f, 0.0f};
            if (a != 0)
                val = *reinterpret_cast<const float4*>(
                    &hin[((size_t)b * Vv + (a - 1)) * CIN + c4 * 4]);
            *reinterpret_cast<float4*>(&s_hnb[g][n][c4 * 4]) = val;
        }
        // Gather neighbor ux, build logits
        for (int j = t; j < NBK * KK; j += 16) {
            int n = j / KK;
            int k = j - n * KK;
            int a = s_adj[g][n];
            float uxn = (a != 0) ? uxin[((size_t)b * Vv + (a - 1)) * KK + k] : 0.0f;
            s_lg[g][n][k] = s_uxs[g][k] + uxn + cvec[k];
        }
    }
    __syncthreads();

    // Softmax over k, per neighbor (lanes t<10)
    if (act && t < NBK) {
        float m = -1e30f;
#pragma unroll
        for (int k = 0; k < KK; k++) m = fmaxf(m, s_lg[g][t][k]);
        float e[KK];
        float s = 0.0f;
#pragma unroll
        for (int k = 0; k < KK; k++) { e[k] = __expf(s_lg[g][t][k] - m); s += e[k]; }
        float r = 1.0f / s;
#pragma unroll
        for (int k = 0; k < KK; k++) s_lg[g][t][k] = e[k] * r;
    }
    __syncthreads();

    // G[k][c] for owned channels c = t (and t+16 if CIN==32)
    float g0[KK], g1[KK];
#pragma unroll
    for (int k = 0; k < KK; k++) { g0[k] = 0.0f; g1[k] = 0.0f; }
    if (act) {
#pragma unroll
        for (int n = 0; n < NBK; n++) {
            float h0 = s_hnb[g][n][t];
            float h1 = (CIN == 32) ? s_hnb[g][n][t + 16] : 0.0f;
#pragma unroll
            for (int k = 0; k < KK; k++) {
                float qv = s_lg[g][n][k];
                g0[k] = fmaf(qv, h0, g0[k]);
                if (CIN == 32) g1[k] = fmaf(qv, h1, g1[k]);
            }
        }
    }

    // E: partial out[o] from owned channels, then 16-lane butterfly reduce
    float acc[COUT];
#pragma unroll
    for (int o = 0; o < COUT; o++) acc[o] = 0.0f;
    if (act) {
#pragma unroll
        for (int k = 0; k < KK; k++) {
#pragma unroll
            for (int o = 0; o < COUT; o++) {
                acc[o] = fmaf(g0[k], s_w[k][o][t], acc[o]);
                if (CIN == 32) acc[o] = fmaf(g1[k], s_w[k][o][t + 16], acc[o]);
            }
        }
    }
#pragma unroll
    for (int o = 0; o < COUT; o++) {
        acc[o] += __shfl_xor(acc[o], 1, 16);
        acc[o] += __shfl_xor(acc[o], 2, 16);
        acc[o] += __shfl_xor(acc[o], 4, 16);
        acc[o] += __shfl_xor(acc[o], 8, 16);
    }

    // Epilogue: scale by recip, +bias, relu; write h / s_hnew
    if (act) {
        float rec = s_rec[g];
        constexpr int O0 = (COUT < 16) ? COUT : 16;
        if (t < O0) {
            float val = fmaxf(acc[t] * rec + bvec[t], 0.0f);
            if (!LAST) hout[(size_t)vv * COUT + t] = val;
            s_hnew[g][t] = val;
        }
        if (COUT == 32) {
            float val = fmaxf(acc[t + 16] * rec + bvec[t + 16], 0.0f);
            hout[(size_t)vv * COUT + t + 16] = val;
            s_hnew[g][t + 16] = val;
        }
    }
    __syncthreads();

    if (!LAST) {
        // Fused ux for next layer: ux[k] = sum_o hnew[o] * unext[o,k]
        if (act && t < KK) {
            float s = 0.0f;
#pragma unroll
            for (int o = 0; o < COUT; o++)
                s = fmaf(s_hnew[g][o], unext[o * KK + t], s);
            uxout[(size_t)vv * KK + t] = s;
        }
    } else {
        // Fused decoder: dout = hnew @ Wout  (3x3)
        if (act && t < 3) {
            float s = 0.0f;
#pragma unroll
            for (int j = 0; j < 3; j++)
                s = fmaf(s_hnew[g][j], unext[j * 3 + t], s);
            dout[(size_t)vv * 3 + t] = s;
        }
    }
}

// ---------------------------------------------------------------------------
extern "C" void kernel_launch(void* const* d_in, const int* in_sizes, int n_in,
                              void* d_out, int out_size, void* d_ws, size_t ws_size,
                              hipStream_t stream)
{
    const float* x    = (const float*)d_in[0];
    const int*   adj  = (const int*)  d_in[1];
    const float* Win  = (const float*)d_in[2];
    const float* Wout = (const float*)d_in[3];
    const float *W[6], *bb[6], *uu[6], *cc[6];
    for (int i = 0; i < 6; i++) {
        W[i]  = (const float*)d_in[4 + 4 * i];
        bb[i] = (const float*)d_in[5 + 4 * i];
        uu[i] = (const float*)d_in[6 + 4 * i];
        cc[i] = (const float*)d_in[7 + 4 * i];
    }
    float* out = (float*)d_out;

    // Workspace layout (floats): hA [TOT*16], hB [TOT*32], uxA [TOT*9], uxB [TOT*9]
    float* hA  = (float*)d_ws;
    float* hB  = hA  + (size_t)TOT * 16;
    float* uxA = hB  + (size_t)TOT * 32;
    float* uxB = uxA + (size_t)TOT * KK;

    int nbv = (TOT + 255) / 256;
    encoder_kernel<<<nbv, 256, 0, stream>>>(x, Win, uu[0], hA, uxA);

    int nb = (TOT + 15) / 16;
    nlayer_kernel<16, 16, false><<<nb, 256, 0, stream>>>(hA, uxA, adj, W[0], bb[0], cc[0], uu[1], hB, uxB, nullptr);
    nlayer_kernel<16, 16, false><<<nb, 256, 0, stream>>>(hB, uxB, adj, W[1], bb[1], cc[1], uu[2], hA, uxA, nullptr);
    nlayer_kernel<16, 32, false><<<nb, 256, 0, stream>>>(hA, uxA, adj, W[2], bb[2], cc[2], uu[3], hB, uxB, nullptr);
    nlayer_kernel<32, 16, false><<<nb, 256, 0, stream>>>(hB, uxB, adj, W[3], bb[3], cc[3], uu[4], hA, uxA, nullptr);
    nlayer_kernel<16, 16, false><<<nb, 256, 0, stream>>>(hA, uxA, adj, W[4], bb[4], cc[4], uu[5], hB, uxB, nullptr);
    nlayer_kernel<16, 3, true ><<<nb, 256, 0, stream>>>(hB, uxB, adj, W[5], bb[5], cc[5], Wout, nullptr, nullptr, out);
}

// Round 2
// 141.526 us; speedup vs baseline: 1.0054x; 1.0054x over previous
//
#include <hip/hip_runtime.h>
#include <hip/hip_cooperative_groups.h>

namespace cg = cooperative_groups;

#define NBK 10
#define KK  9

constexpr int Bv  = 4;
constexpr int Vv  = 5023;
constexpr int TOT = Bv * Vv;   // 20092
constexpr int NBLK = 628;      // cooperative grid; 2 vertex-groups of 16 per block
constexpr int UXP  = 12;       // padded ux row stride (float4-friendly)

struct KArgs {
    const float* x; const int* adj; const float* Win; const float* Wout;
    const float* W[6]; const float* b[6]; const float* u[6]; const float* c[6];
    float* hA; float* hB; float* uxA; float* uxB; float* out;
};

// ---------------------------------------------------------------------------
// One NLayer inside the fused kernel. 16 lanes per vertex, 16 vertices per
// block-iteration, 2 iterations per block. Lane t owns input channel t
// (and t+16 when CIN==32).
// ---------------------------------------------------------------------------
template<int CIN, int COUT, bool LAST>
__device__ __forceinline__ void nlayer_step(
    int bid, int tid,
    const float* __restrict__ hin, const float* __restrict__ uxin,
    const int* __restrict__ adj,
    const float* __restrict__ W, const float* __restrict__ bvec,
    const float* __restrict__ cvec, const float* __restrict__ unx,
    float* __restrict__ hout, float* __restrict__ uxout, float* __restrict__ dout,
    float* s_w, float (*s_q)[NBK][UXP])
{
    constexpr int COUTP = (COUT == 32) ? 36 : ((COUT == 16) ? 20 : 4);
    constexpr int ACCN  = ((COUT + 3) / 4) * 4;

    // Stage W transposed to [k][c][o] with padded o-stride (coalesced global,
    // 2-way-max LDS write conflicts).
    for (int i = tid; i < CIN * KK * COUT; i += 256) {
        int c   = i / (KK * COUT);
        int rem = i - c * (KK * COUT);
        int k   = rem / COUT;
        int o   = rem - k * COUT;
        s_w[(k * CIN + c) * COUTP + o] = W[i];
    }
    float cv[KK];
#pragma unroll
    for (int k = 0; k < KK; k++) cv[k] = cvec[k];
    __syncthreads();

    const int g = tid >> 4;
    const int t = tid & 15;

#pragma unroll 1
    for (int it = 0; it < 2; ++it) {
        const int grp = bid + it * NBLK;
        const int vv  = grp * 16 + g;
        const bool act = vv < TOT;

        int nb[NBK];
        if (act) {
            const int b0 = vv / Vv;
            const int v  = vv - b0 * Vv;
            const int2* arow = reinterpret_cast<const int2*>(&adj[v * NBK]);
#pragma unroll
            for (int j = 0; j < 5; j++) { int2 p = arow[j]; nb[2 * j] = p.x; nb[2 * j + 1] = p.y; }
        } else {
#pragma unroll
            for (int n = 0; n < NBK; n++) nb[n] = 0;
        }
        const int b = (act ? vv : 0) / Vv;

        int cnt = 0;
#pragma unroll
        for (int n = 0; n < NBK; n++) cnt += (nb[n] != 0) ? 1 : 0;
        const float rec = (cnt > 0) ? (1.0f / (float)cnt) : 0.0f;

        // Register gather of neighbor features for owned channel(s)
        float hn0[NBK], hn1[NBK];
#pragma unroll
        for (int n = 0; n < NBK; n++) {
            const int a = nb[n];
            const size_t hbase = ((size_t)b * Vv + (a - 1)) * CIN;
            hn0[n] = a ? hin[hbase + t] : 0.0f;
            if constexpr (CIN == 32) hn1[n] = a ? hin[hbase + t + 16] : 0.0f;
            else                     hn1[n] = 0.0f;
        }

        // Lanes t<10: per-neighbor softmax fully in registers -> s_q
        if (act && t < NBK) {
            const float4* su4 = reinterpret_cast<const float4*>(&uxin[(size_t)vv * UXP]);
            const float4 s0 = su4[0], s1 = su4[1];
            const float  s8 = uxin[(size_t)vv * UXP + 8];
            const int a = nb[t];
            float4 n0 = {0, 0, 0, 0}, n1 = {0, 0, 0, 0};
            float  n8 = 0.0f;
            if (a) {
                const size_t ub = ((size_t)b * Vv + (a - 1)) * UXP;
                const float4* nu4 = reinterpret_cast<const float4*>(&uxin[ub]);
                n0 = nu4[0]; n1 = nu4[1]; n8 = uxin[ub + 8];
            }
            float lg[KK] = { s0.x + n0.x + cv[0], s0.y + n0.y + cv[1],
                             s0.z + n0.z + cv[2], s0.w + n0.w + cv[3],
                             s1.x + n1.x + cv[4], s1.y + n1.y + cv[5],
                             s1.z + n1.z + cv[6], s1.w + n1.w + cv[7],
                             s8 + n8 + cv[8] };
            float m = lg[0];
#pragma unroll
            for (int k = 1; k < KK; k++) m = fmaxf(m, lg[k]);
            float e[KK], sum = 0.0f;
#pragma unroll
            for (int k = 0; k < KK; k++) { e[k] = __expf(lg[k] - m); sum += e[k]; }
            const float r = 1.0f / sum;
            *reinterpret_cast<float4*>(&s_q[g][t][0]) =
                make_float4(e[0] * r, e[1] * r, e[2] * r, e[3] * r);
            *reinterpret_cast<float4*>(&s_q[g][t][4]) =
                make_float4(e[4] * r, e[5] * r, e[6] * r, e[7] * r);
            s_q[g][t][8] = e[8] * r;
        }
        __syncthreads();

        // G[k] for owned channel(s): g0/g1[k] = sum_n q[n][k]*h_nb[n][c]
        float g0[KK], g1[KK];
#pragma unroll
        for (int k = 0; k < KK; k++) { g0[k] = 0.0f; g1[k] = 0.0f; }
#pragma unroll
        for (int n = 0; n < NBK; n++) {
            const float4 qa = *reinterpret_cast<const float4*>(&s_q[g][n][0]);
            const float4 qb = *reinterpret_cast<const float4*>(&s_q[g][n][4]);
            const float  q8 = s_q[g][n][8];
            const float h0 = hn0[n];
            g0[0] = fmaf(qa.x, h0, g0[0]); g0[1] = fmaf(qa.y, h0, g0[1]);
            g0[2] = fmaf(qa.z, h0, g0[2]); g0[3] = fmaf(qa.w, h0, g0[3]);
            g0[4] = fmaf(qb.x, h0, g0[4]); g0[5] = fmaf(qb.y, h0, g0[5]);
            g0[6] = fmaf(qb.z, h0, g0[6]); g0[7] = fmaf(qb.w, h0, g0[7]);
            g0[8] = fmaf(q8,   h0, g0[8]);
            if constexpr (CIN == 32) {
                const float h1 = hn1[n];
                g1[0] = fmaf(qa.x, h1, g1[0]); g1[1] = fmaf(qa.y, h1, g1[1]);
                g1[2] = fmaf(qa.z, h1, g1[2]); g1[3] = fmaf(qa.w, h1, g1[3]);
                g1[4] = fmaf(qb.x, h1, g1[4]); g1[5] = fmaf(qb.y, h1, g1[5]);
                g1[6] = fmaf(qb.z, h1, g1[6]); g1[7] = fmaf(qb.w, h1, g1[7]);
                g1[8] = fmaf(q8,   h1, g1[8]);
            }
        }

        // E-phase: acc[o] += g[k]*W[c=t][k][o] via ds_read_b128
        float acc[ACCN];
#pragma unroll
        for (int o = 0; o < ACCN; o++) acc[o] = 0.0f;
#pragma unroll
        for (int k = 0; k < KK; k++) {
            const float g0k = g0[k];
            const float* wr = &s_w[(k * CIN + t) * COUTP];
#pragma unroll
            for (int o4 = 0; o4 < ACCN / 4; o4++) {
                const float4 w = *reinterpret_cast<const float4*>(&wr[4 * o4]);
                acc[4 * o4 + 0] = fmaf(g0k, w.x, acc[4 * o4 + 0]);
                acc[4 * o4 + 1] = fmaf(g0k, w.y, acc[4 * o4 + 1]);
                acc[4 * o4 + 2] = fmaf(g0k, w.z, acc[4 * o4 + 2]);
                acc[4 * o4 + 3] = fmaf(g0k, w.w, acc[4 * o4 + 3]);
            }
            if constexpr (CIN == 32) {
                const float g1k = g1[k];
                const float* wr2 = &s_w[(k * CIN + t + 16) * COUTP];
#pragma unroll
                for (int o4 = 0; o4 < ACCN / 4; o4++) {
                    const float4 w = *reinterpret_cast<const float4*>(&wr2[4 * o4]);
                    acc[4 * o4 + 0] = fmaf(g1k, w.x, acc[4 * o4 + 0]);
                    acc[4 * o4 + 1] = fmaf(g1k, w.y, acc[4 * o4 + 1]);
                    acc[4 * o4 + 2] = fmaf(g1k, w.z, acc[4 * o4 + 2]);
                    acc[4 * o4 + 3] = fmaf(g1k, w.w, acc[4 * o4 + 3]);
                }
            }
        }

        // 16-lane xor all-reduce (every lane ends with all sums)
#pragma unroll
        for (int o = 0; o < COUT; o++) {
            acc[o] += __shfl_xor(acc[o], 1, 16);
            acc[o] += __shfl_xor(acc[o], 2, 16);
            acc[o] += __shfl_xor(acc[o], 4, 16);
            acc[o] += __shfl_xor(acc[o], 8, 16);
        }

        if (act) {
            float hnew[COUT];
#pragma unroll
            for (int o = 0; o < COUT; o++)
                hnew[o] = fmaxf(fmaf(acc[o], rec, bvec[o]), 0.0f);

            if constexpr (!LAST) {
                // h write: select owned element with static-index cndmask chain
                float val0 = hnew[0];
#pragma unroll
                for (int o = 1; o < ((COUT < 16) ? COUT : 16); o++)
                    val0 = (t == o) ? hnew[o] : val0;
                hout[(size_t)vv * COUT + t] = val0;
                if constexpr (COUT == 32) {
                    float val1 = hnew[16];
#pragma unroll
                    for (int o = 17; o < 32; o++)
                        val1 = (t == (o - 16)) ? hnew[o] : val1;
                    hout[(size_t)vv * COUT + 16 + t] = val1;
                }
                // fused ux for next layer
                if (t < KK) {
                    float s = 0.0f;
#pragma unroll
                    for (int o = 0; o < COUT; o++)
                        s = fmaf(hnew[o], unx[o * KK + t], s);
                    uxout[(size_t)vv * UXP + t] = s;
                }
            } else {
                if (t < 3) {
                    float s = 0.0f;
#pragma unroll
                    for (int j = 0; j < 3; j++)
                        s = fmaf(hnew[j], unx[j * 3 + t], s);
                    dout[(size_t)vv * 3 + t] = s;
                }
            }
        }
    }
}

// ---------------------------------------------------------------------------
__global__ __launch_bounds__(256, 3) void fused_kernel(KArgs A)
{
    __shared__ __align__(16) float s_w[5760];                 // max 9*32*20
    __shared__ __align__(16) float s_q[16][NBK][UXP];

    const int tid = threadIdx.x;
    const int bid = blockIdx.x;
    cg::grid_group grid = cg::this_grid();

    // Encoder: h0 = relu(x@Win), ux0 = h0@u0
    for (int idx = bid * 256 + tid; idx < TOT; idx += NBLK * 256) {
        const float x0 = A.x[idx * 3 + 0], x1 = A.x[idx * 3 + 1], x2 = A.x[idx * 3 + 2];
        float hv[16];
#pragma unroll
        for (int c = 0; c < 16; c++) {
            float s = x0 * A.Win[c] + x1 * A.Win[16 + c] + x2 * A.Win[32 + c];
            hv[c] = fmaxf(s, 0.0f);
        }
        float4* hw = reinterpret_cast<float4*>(&A.hA[(size_t)idx * 16]);
#pragma unroll
        for (int j = 0; j < 4; j++)
            hw[j] = make_float4(hv[4 * j], hv[4 * j + 1], hv[4 * j + 2], hv[4 * j + 3]);
#pragma unroll
        for (int k = 0; k < KK; k++) {
            float s = 0.0f;
#pragma unroll
            for (int c = 0; c < 16; c++) s = fmaf(hv[c], A.u[0][c * KK + k], s);
            A.uxA[(size_t)idx * UXP + k] = s;
        }
    }
    grid.sync();
    nlayer_step<16, 16, false>(bid, tid, A.hA, A.uxA, A.adj, A.W[0], A.b[0], A.c[0], A.u[1], A.hB, A.uxB, nullptr, s_w, s_q);
    grid.sync();
    nlayer_step<16, 16, false>(bid, tid, A.hB, A.uxB, A.adj, A.W[1], A.b[1], A.c[1], A.u[2], A.hA, A.uxA, nullptr, s_w, s_q);
    grid.sync();
    nlayer_step<16, 32, false>(bid, tid, A.hA, A.uxA, A.adj, A.W[2], A.b[2], A.c[2], A.u[3], A.hB, A.uxB, nullptr, s_w, s_q);
    grid.sync();
    nlayer_step<32, 16, false>(bid, tid, A.hB, A.uxB, A.adj, A.W[3], A.b[3], A.c[3], A.u[4], A.hA, A.uxA, nullptr, s_w, s_q);
    grid.sync();
    nlayer_step<16, 16, false>(bid, tid, A.hA, A.uxA, A.adj, A.W[4], A.b[4], A.c[4], A.u[5], A.hB, A.uxB, nullptr, s_w, s_q);
    grid.sync();
    nlayer_step<16, 3, true >(bid, tid, A.hB, A.uxB, A.adj, A.W[5], A.b[5], A.c[5], A.Wout, nullptr, nullptr, A.out, s_w, s_q);
}

// ===========================================================================
// Fallback path (round-0 verified kernels), used only if cooperative launch
// is unavailable. ux stride here is KK (9).
// ===========================================================================
__global__ __launch_bounds__(256) void fb_encoder(
    const float* __restrict__ x, const float* __restrict__ Win,
    const float* __restrict__ u0, float* __restrict__ h, float* __restrict__ ux)
{
    int vv = blockIdx.x * 256 + threadIdx.x;
    if (vv >= TOT) return;
    float x0 = x[vv * 3 + 0], x1 = x[vv * 3 + 1], x2 = x[vv * 3 + 2];
    float hv[16];
#pragma unroll
    for (int c = 0; c < 16; c++) {
        float s = x0 * Win[c] + x1 * Win[16 + c] + x2 * Win[32 + c];
        hv[c] = fmaxf(s, 0.0f);
        h[(size_t)vv * 16 + c] = hv[c];
    }
#pragma unroll
    for (int k = 0; k < KK; k++) {
        float s = 0.0f;
#pragma unroll
        for (int c = 0; c < 16; c++) s = fmaf(hv[c], u0[c * KK + k], s);
        ux[(size_t)vv * KK + k] = s;
    }
}

template<int CIN, int COUT, bool LAST>
__global__ __launch_bounds__(256) void fb_nlayer(
    const float* __restrict__ hin, const float* __restrict__ uxin,
    const int* __restrict__ adj, const float* __restrict__ W,
    const float* __restrict__ bvec, const float* __restrict__ cvec,
    const float* __restrict__ unext, float* __restrict__ hout,
    float* __restrict__ uxout, float* __restrict__ dout)
{
    constexpr int CP = CIN + 4;
    constexpr int WP = CIN + 1;
    __shared__ __align__(16) float s_hnb[16][NBK][CP];
    __shared__ float s_lg[16][NBK][KK];
    __shared__ float s_uxs[16][KK];
    __shared__ int   s_adj[16][NBK];
    __shared__ float s_rec[16];
    __shared__ float s_hnew[16][COUT];
    __shared__ float s_w[KK][COUT][WP];

    const int tid = threadIdx.x;
    const int g = tid >> 4;
    const int t = tid & 15;
    const int vv = blockIdx.x * 16 + g;
    const bool act = vv < TOT;
    int b = 0, v = 0;
    if (act) { b = vv / Vv; v = vv - b * Vv; }

    for (int i = tid; i < CIN * KK * COUT; i += 256) {
        int c = i / (KK * COUT);
        int rem = i - c * (KK * COUT);
        int k = rem / COUT;
        int o = rem - k * COUT;
        s_w[k][o][c] = W[i];
    }
    if (act) {
        if (t < NBK) s_adj[g][t] = adj[v * NBK + t];
        if (t < KK)  s_uxs[g][t] = uxin[(size_t)vv * KK + t];
    }
    __syncthreads();
    if (act && t == 0) {
        int cnt = 0;
#pragma unroll
        for (int n = 0; n < NBK; n++) cnt += (s_adj[g][n] != 0) ? 1 : 0;
        s_rec[g] = (cnt > 0) ? (1.0f / (float)cnt) : 0.0f;
    }
    if (act) {
        constexpr int U = NBK * CIN / 4;
        for (int j = t; j < U; j += 16) {
            int n  = j / (CIN / 4);
            int c4 = j - n * (CIN / 4);
            int a = s_adj[g][n];
            float4 val = {0.0f, 0.0f, 0.0f, 0.0f};
            if (a != 0)
                val = *reinterpret_cast<const float4*>(&hin[((size_t)b * Vv + (a - 1)) * CIN + c4 * 4]);
            *reinterpret_cast<float4*>(&s_hnb[g][n][c4 * 4]) = val;
        }
        for (int j = t; j < NBK * KK; j += 16) {
            int n = j / KK;
            int k = j - n * KK;
            int a = s_adj[g][n];
            float uxn = (a != 0) ? uxin[((size_t)b * Vv + (a - 1)) * KK + k] : 0.0f;
            s_lg[g][n][k] = s_uxs[g][k] + uxn + cvec[k];
        }
    }
    __syncthreads();
    if (act && t < NBK) {
        float m = -1e30f;
#pragma unroll
        for (int k = 0; k < KK; k++) m = fmaxf(m, s_lg[g][t][k]);
        float e[KK];
        float s = 0.0f;
#pragma unroll
        for (int k = 0; k < KK; k++) { e[k] = __expf(s_lg[g][t][k] - m); s += e[k]; }
        float r = 1.0f / s;
#pragma unroll
        for (int k = 0; k < KK; k++) s_lg[g][t][k] = e[k] * r;
    }
    __syncthreads();
    float g0[KK], g1[KK];
#pragma unroll
    for (int k = 0; k < KK; k++) { g0[k] = 0.0f; g1[k] = 0.0f; }
    if (act) {
#pragma unroll
        for (int n = 0; n < NBK; n++) {
            float h0 = s_hnb[g][n][t];
            float h1 = (CIN == 32) ? s_hnb[g][n][t + 16] : 0.0f;
#pragma unroll
            for (int k = 0; k < KK; k++) {
                float qv = s_lg[g][n][k];
                g0[k] = fmaf(qv, h0, g0[k]);
                if (CIN == 32) g1[k] = fmaf(qv, h1, g1[k]);
            }
        }
    }
    float acc[COUT];
#pragma unroll
    for (int o = 0; o < COUT; o++) acc[o] = 0.0f;
    if (act) {
#pragma unroll
        for (int k = 0; k < KK; k++) {
#pragma unroll
            for (int o = 0; o < COUT; o++) {
                acc[o] = fmaf(g0[k], s_w[k][o][t], acc[o]);
                if (CIN == 32) acc[o] = fmaf(g1[k], s_w[k][o][t + 16], acc[o]);
            }
        }
    }
#pragma unroll
    for (int o = 0; o < COUT; o++) {
        acc[o] += __shfl_xor(acc[o], 1, 16);
        acc[o] += __shfl_xor(acc[o], 2, 16);
        acc[o] += __shfl_xor(acc[o], 4, 16);
        acc[o] += __shfl_xor(acc[o], 8, 16);
    }
    if (act) {
        float rec = s_rec[g];
        constexpr int O0 = (COUT < 16) ? COUT : 16;
        if (t < O0) {
            float val = fmaxf(acc[t] * rec + bvec[t], 0.0f);
            if (!LAST) hout[(size_t)vv * COUT + t] = val;
            s_hnew[g][t] = val;
        }
        if (COUT == 32) {
            float val = fmaxf(acc[t + 16] * rec + bvec[t + 16], 0.0f);
            hout[(size_t)vv * COUT + t + 16] = val;
            s_hnew[g][t + 16] = val;
        }
    }
    __syncthreads();
    if (!LAST) {
        if (act && t < KK) {
            float s = 0.0f;
#pragma unroll
            for (int o = 0; o < COUT; o++)
                s = fmaf(s_hnew[g][o], unext[o * KK + t], s);
            uxout[(size_t)vv * KK + t] = s;
        }
    } else {
        if (act && t < 3) {
            float s = 0.0f;
#pragma unroll
            for (int j = 0; j < 3; j++)
                s = fmaf(s_hnew[g][j], unext[j * 3 + t], s);
            dout[(size_t)vv * 3 + t] = s;
        }
    }
}

// ---------------------------------------------------------------------------
extern "C" void kernel_launch(void* const* d_in, const int* in_sizes, int n_in,
                              void* d_out, int out_size, void* d_ws, size_t ws_size,
                              hipStream_t stream)
{
    const float* x    = (const float*)d_in[0];
    const int*   adj  = (const int*)  d_in[1];
    const float* Win  = (const float*)d_in[2];
    const float* Wout = (const float*)d_in[3];
    const float *W[6], *bb[6], *uu[6], *cc[6];
    for (int i = 0; i < 6; i++) {
        W[i]  = (const float*)d_in[4 + 4 * i];
        bb[i] = (const float*)d_in[5 + 4 * i];
        uu[i] = (const float*)d_in[6 + 4 * i];
        cc[i] = (const float*)d_in[7 + 4 * i];
    }
    float* out = (float*)d_out;

    // Workspace: hA [TOT*16], hB [TOT*32], uxA/uxB [TOT*UXP]
    float* hA  = (float*)d_ws;
    float* hB  = hA  + (size_t)TOT * 16;
    float* uxA = hB  + (size_t)TOT * 32;
    float* uxB = uxA + (size_t)TOT * UXP;

    // Decide cooperative path (host-side queries; deterministic, capture-safe)
    int coop_attr = 0, dev = 0, maxb = 0;
    (void)hipGetDevice(&dev);
    (void)hipDeviceGetAttribute(&coop_attr, hipDeviceAttributeCooperativeLaunch, dev);
    hipError_t oe = hipOccupancyMaxActiveBlocksPerMultiprocessor(&maxb, fused_kernel, 256, 0);
    bool use_coop = (coop_attr != 0) && (oe == hipSuccess) && (maxb >= 3);

    if (use_coop) {
        KArgs A;
        A.x = x; A.adj = adj; A.Win = Win; A.Wout = Wout;
        for (int i = 0; i < 6; i++) { A.W[i] = W[i]; A.b[i] = bb[i]; A.u[i] = uu[i]; A.c[i] = cc[i]; }
        A.hA = hA; A.hB = hB; A.uxA = uxA; A.uxB = uxB; A.out = out;
        void* params[] = { &A };
        hipError_t le = hipLaunchCooperativeKernel(fused_kernel, dim3(NBLK), dim3(256),
                                                   params, 0, stream);
        if (le == hipSuccess) return;
    }

    // Fallback: 7-kernel verified path (ux stride = KK)
    float* uxA9 = uxA;   // reuse same regions; strides differ but capacity is ample
    float* uxB9 = uxB;
    int nbv = (TOT + 255) / 256;
    fb_encoder<<<nbv, 256, 0, stream>>>(x, Win, uu[0], hA, uxA9);
    int nb = (TOT + 15) / 16;
    fb_nlayer<16, 16, false><<<nb, 256, 0, stream>>>(hA, uxA9, adj, W[0], bb[0], cc[0], uu[1], hB, uxB9, nullptr);
    fb_nlayer<16, 16, false><<<nb, 256, 0, stream>>>(hB, uxB9, adj, W[1], bb[1], cc[1], uu[2], hA, uxA9, nullptr);
    fb_nlayer<16, 32, false><<<nb, 256, 0, stream>>>(hA, uxA9, adj, W[2], bb[2], cc[2], uu[3], hB, uxB9, nullptr);
    fb_nlayer<32, 16, false><<<nb, 256, 0, stream>>>(hB, uxB9, adj, W[3], bb[3], cc[3], uu[4], hA, uxA9, nullptr);
    fb_nlayer<16, 16, false><<<nb, 256, 0, stream>>>(hA, uxA9, adj, W[4], bb[4], cc[4], uu[5], hB, uxB9, nullptr);
    fb_nlayer<16, 3, true ><<<nb, 256, 0, stream>>>(hB, uxB9, adj, W[5], bb[5], cc[5], Wout, nullptr, nullptr, out);
}